// Round 8
// baseline (477.472 us; speedup 1.0000x reference)
//
#include <hip/hip_runtime.h>
#include <hip/hip_cooperative_groups.h>
#include <math.h>

namespace cg = cooperative_groups;

#define VIF_EPS       1e-10f
#define SIGMA_NSQ     2.0f
#define SIGMA_MAX_INV (4.0f / (255.0f * 255.0f))
#define GAIN_LIMIT    100.0f

// jnp.pad mode='reflect' (no edge duplication). Overshoot < dim, single reflection suffices.
__device__ __forceinline__ int reflect_idx(int i, int n) {
    i = (i < 0) ? -i : i;
    i = (i >= n) ? (2 * n - 2 - i) : i;
    return i;
}

// Reference: sigma=N/5; g=exp(-x^2/(2 sigma^2)); win=outer(g,g)/sum -> separable gn = g/sum(g).
template <int N>
__device__ __forceinline__ void compute_weights(float* wts) {
    if (threadIdx.x == 0) {
        const float sigma = (float)N / 5.0f;
        const float denom = 2.0f * sigma * sigma;
        float s = 0.0f;
        for (int i = 0; i < N; ++i) {
            float x = (float)i - (float)(N - 1) * 0.5f;
            float g = expf(-(x * x) / denom);
            wts[i] = g;
            s += g;
        }
        for (int i = 0; i < N; ++i) wts[i] = wts[i] / s;
    }
}

constexpr int tile_w(int N) { return (128 - (N - 1)) & ~3; }  // 17->112, 9->120, 5/3->124
constexpr int cdiv(int a, int b) { return (a + b - 1) / b; }

// ---- pyramid constants (compile-time) ----
constexpr int B_ = 4;
constexpr int H0_ = 1080, W0_ = 1920;
constexpr int H1_ = 540,  W1_ = 960;
constexpr int H2_ = 270,  W2_ = 480;
constexpr int H3_ = 135,  W3_ = 240;

constexpr int SX0 = cdiv(W0_, tile_w(17)), SY0 = cdiv(H0_, 8), N0_ = SX0 * SY0;  // 18x135=2430
constexpr int SX1 = cdiv(W1_, tile_w(9)),  SY1 = cdiv(H1_, 8), N1_ = SX1 * SY1;  // 8x68=544
constexpr int SX2 = cdiv(W2_, tile_w(5)),  SY2 = cdiv(H2_, 8), N2_ = SX2 * SY2;  // 4x34=136
constexpr int SX3 = cdiv(W3_, tile_w(3)),  SY3 = cdiv(H3_, 8), N3_ = SX3 * SY3;  // 2x17=34

constexpr int DGX1 = W1_ / 120, ND1_ = DGX1 * cdiv(H1_, 8);  // 8x68=544
constexpr int DGX2 = W2_ / 120, ND2_ = DGX2 * cdiv(H2_, 8);  // 4x34=136
constexpr int DGX3 = W3_ / 120, ND3_ = DGX3 * cdiv(H3_, 8);  // 2x17=34

// ---- static shared layouts ----
template <int N>
struct StatsSmem {
    float v[5][8][132];   // row stride 528 B = 33*16 -> float4-clean
    float wts[N];
    float rsum[8];
};
template <int N>
struct DownSmem {
    float vb[2][8][252];
    float wts[N];
};

// ---------------- stats body (vertical-first separable VIF; R7-proven) ----------------
// bx flattened Y-MAJOR (ytile = bx % sy) for L2 reuse of vertical halos.
// VGPR discipline: NO min-waves launch bound (R3: 930 MB spill), 4-wide phase 2
// (R5: 8-wide -> VGPR 96 -> occupancy collapse).
template <int N>
__device__ __forceinline__ void stats_body(
    StatsSmem<N>& sm, const float* __restrict__ refp, const float* __restrict__ distp,
    int h, int w, float shift, double2* __restrict__ partial,
    int sy, int sx, int bx, int b) {
    constexpr int P   = (N - 1) / 2;
    constexpr int VC  = 128;
    constexpr int TW  = tile_w(N);
    constexpr int TH  = 8;
    constexpr int Q   = 4;
    constexpr int LR  = Q + 2 * P;
    constexpr int XG  = TW / 4;
    constexpr int F4  = (N + 6) / 4;

    const int tid = threadIdx.x;
    const int ytile = bx % sy;
    const int xtile = bx / sy;
    const int x0 = xtile * TW;
    const int y0 = ytile * TH;

    compute_weights<N>(sm.wts);
    __syncthreads();

    float wr[N];
#pragma unroll
    for (int j = 0; j < N; ++j) wr[j] = sm.wts[j];

    // ---- Phase 1: vertical conv from global ----
    {
        const int c = tid & (VC - 1);
        const int g = tid >> 7;
        const int gx = reflect_idx(x0 + c - P, w);
        const float* rb = refp  + (size_t)b * h * w + gx;
        const float* db = distp + (size_t)b * h * w + gx;

        float acc[5][Q];
#pragma unroll
        for (int ch = 0; ch < 5; ++ch)
#pragma unroll
            for (int q = 0; q < Q; ++q) acc[ch][q] = 0.f;

        auto acc_push = [&](int i, float r, float d) {
            float p2 = r * r, p3 = d * d, p4 = r * d;
#pragma unroll
            for (int q = 0; q < Q; ++q) {
                int j = i - q;
                if (j >= 0 && j < N) {
                    float wj = wr[j];
                    acc[0][q] += wj * r;
                    acc[1][q] += wj * d;
                    acc[2][q] += wj * p2;
                    acc[3][q] += wj * p3;
                    acc[4][q] += wj * p4;
                }
            }
        };

        const int rowlo = y0 + g * Q - P;
        if (rowlo >= 0 && rowlo + LR <= h) {
            // Interior fast path (wave-uniform): pointer walk, no reflect per row.
            const float* pr = rb + (size_t)rowlo * w;
            const float* pd = db + (size_t)rowlo * w;
#pragma unroll
            for (int i = 0; i < LR; ++i) {
                float r = pr[0] - shift;
                float d = pd[0] - shift;
                pr += w; pd += w;
                acc_push(i, r, d);
            }
        } else {
#pragma unroll
            for (int i = 0; i < LR; ++i) {
                int gy = reflect_idx(rowlo + i, h);
                float r = rb[(size_t)gy * w] - shift;
                float d = db[(size_t)gy * w] - shift;
                acc_push(i, r, d);
            }
        }
#pragma unroll
        for (int ch = 0; ch < 5; ++ch)
#pragma unroll
            for (int q = 0; q < Q; ++q)
                sm.v[ch][g * Q + q][c] = acc[ch][q];
    }
    __syncthreads();

    // ---- Phase 2: horizontal conv + VIF math (4 outputs/thread) ----
    float num_v = 0.f, den_v = 0.f;
    {
        const int xg  = tid & 31;
        const int row = tid >> 5;
        if (xg < XG) {
            float mu[5][4];
#pragma unroll
            for (int ch = 0; ch < 5; ++ch) {
                float win[F4 * 4];
                const float4* s4 = (const float4*)&sm.v[ch][row][xg * 4];
#pragma unroll
                for (int f = 0; f < F4; ++f) {
                    float4 t = s4[f];
                    win[4 * f + 0] = t.x; win[4 * f + 1] = t.y;
                    win[4 * f + 2] = t.z; win[4 * f + 3] = t.w;
                }
#pragma unroll
                for (int q = 0; q < 4; ++q) {
                    float a = 0.f;
#pragma unroll
                    for (int j = 0; j < N; ++j) a += wr[j] * win[q + j];
                    mu[ch][q] = a;
                }
            }
            const int gy = y0 + row;
#pragma unroll
            for (int q = 0; q < 4; ++q) {
                int gx = x0 + xg * 4 + q;
                if (gx < w && gy < h) {
                    float mu1 = mu[0][q], mu2 = mu[1][q];
                    float s1  = fmaxf(0.f, mu[2][q] - mu1 * mu1);
                    float s2  = fmaxf(0.f, mu[3][q] - mu2 * mu2);
                    float s12 = mu[4][q] - mu1 * mu2;

                    float g  = s12 / (s1 + VIF_EPS);
                    float sv = s2 - g * s12;
                    if (s1 < VIF_EPS) { g = 0.f; sv = s2; s1 = 0.f; }
                    if (s2 < VIF_EPS) { g = 0.f; sv = 0.f; }
                    if (g  < 0.f)     { sv = s2; g = 0.f; }
                    if (sv <= VIF_EPS) sv = VIF_EPS;
                    g = fminf(g, GAIN_LIMIT);

                    float num_ar = __log2f(1.f + g * g * s1 / (sv + SIGMA_NSQ));
                    float den_ar = __log2f(1.f + s1 / SIGMA_NSQ);
                    if (s12 < 0.f) num_ar = 0.f;
                    if (s1 < SIGMA_NSQ) { num_ar = 1.f - s2 * SIGMA_MAX_INV; den_ar = 1.f; }
                    num_v += num_ar;
                    den_v += den_ar;
                }
            }
        }
    }

    // Block reduction.
#pragma unroll
    for (int off = 32; off > 0; off >>= 1) {
        num_v += __shfl_down(num_v, off);
        den_v += __shfl_down(den_v, off);
    }
    const int wid = tid >> 6, lane = tid & 63;
    if (lane == 0) { sm.rsum[wid] = num_v; sm.rsum[4 + wid] = den_v; }
    __syncthreads();
    if (tid == 0) {
        float ns = sm.rsum[0] + sm.rsum[1] + sm.rsum[2] + sm.rsum[3];
        float ds = sm.rsum[4] + sm.rsum[5] + sm.rsum[6] + sm.rsum[7];
        partial[(size_t)b * (sy * sx) + bx] = make_double2((double)ns, (double)ds);
    }
}

// ---------------- downsample body: vertical-first, 120x8 output tile (R7-proven) ----------------
template <int N>
__device__ __forceinline__ void down_body(
    DownSmem<N>& sm, const float* __restrict__ rin, const float* __restrict__ din,
    float* __restrict__ rout, float* __restrict__ dout,
    int h, int w, int h2, int w2, float shift, int dgx, int bx, int b) {
    constexpr int P   = (N - 1) / 2;
    constexpr int TOW = 120, TOH = 8;
    constexpr int IC  = 2 * (TOW - 1) + N;
    constexpr int NR  = 2 * (TOH - 1) + N;
    constexpr int XGn = TOW / 8;
    constexpr int WL  = 14 + N;
    constexpr int F4n = (WL + 3) / 4;

    compute_weights<N>(sm.wts);
    __syncthreads();

    float wr[N];
#pragma unroll
    for (int j = 0; j < N; ++j) wr[j] = sm.wts[j];

    const int tid = threadIdx.x;
    const int xt  = bx % dgx;
    const int yt  = bx / dgx;
    const int x0  = xt * TOW;
    const int y0  = yt * TOH;

    // ---- Vertical decimating pass ----
    if (tid < IC) {
        const int gx = reflect_idx(2 * x0 - P + tid, w);
        const int rowlo = 2 * y0 - P;
        const bool interior = (rowlo >= 0) && (rowlo + NR <= h);
#pragma unroll
        for (int img = 0; img < 2; ++img) {
            const float* src = (img ? din : rin) + (size_t)b * h * w + gx;
            float rows[NR];
            if (interior) {
                const float* p = src + (size_t)rowlo * w;
#pragma unroll
                for (int i = 0; i < NR; ++i) { rows[i] = p[0] - shift; p += w; }
            } else {
#pragma unroll
                for (int i = 0; i < NR; ++i)
                    rows[i] = src[(size_t)reflect_idx(rowlo + i, h) * w] - shift;
            }
#pragma unroll
            for (int t = 0; t < TOH; ++t) {
                float a = 0.f;
#pragma unroll
                for (int j = 0; j < N; ++j) a += wr[j] * rows[2 * t + j];
                sm.vb[img][t][tid] = a;
            }
        }
    }
    __syncthreads();

    // ---- Horizontal decimating pass ----
    if (tid < 2 * TOH * XGn) {
        const int img = tid / (TOH * XGn);
        const int rem = tid - img * (TOH * XGn);
        const int row = rem / XGn;
        const int xg  = rem - row * XGn;

        float win[F4n * 4];
        const float4* s4 = (const float4*)&sm.vb[img][row][16 * xg];
#pragma unroll
        for (int f = 0; f < F4n; ++f) {
            float4 t = s4[f];
            win[4 * f + 0] = t.x; win[4 * f + 1] = t.y;
            win[4 * f + 2] = t.z; win[4 * f + 3] = t.w;
        }
        float o[8];
#pragma unroll
        for (int q = 0; q < 8; ++q) {
            float a = 0.f;
#pragma unroll
            for (int j = 0; j < N; ++j) a += wr[j] * win[2 * q + j];
            o[q] = a;
        }
        const int gy = y0 + row;
        if (gy < h2) {
            float* outp = (img ? dout : rout) + (size_t)b * h2 * w2
                        + (size_t)gy * w2 + x0 + 8 * xg;
            *(float4*)outp       = make_float4(o[0], o[1], o[2], o[3]);
            *(float4*)(outp + 4) = make_float4(o[4], o[5], o[6], o[7]);
        }
    }
}

// ---------------- reduce body ----------------
__device__ __forceinline__ void reduce_body(
    const double2* __restrict__ part, float* __restrict__ out,
    int s, int b, double* scratch) {
    constexpr int RBASE[4] = {0, B_ * N0_, B_ * (N0_ + N1_), B_ * (N0_ + N1_ + N2_)};
    constexpr int RCNT[4]  = {N0_, N1_, N2_, N3_};
    const int base = RBASE[s];
    const int cnt  = RCNT[s];
    const double2* p = part + base + (size_t)b * cnt;

    double ns = 0.0, ds = 0.0;
    for (int i = threadIdx.x; i < cnt; i += 256) {
        double2 v = p[i];
        ns += v.x;
        ds += v.y;
    }
#pragma unroll
    for (int off = 32; off > 0; off >>= 1) {
        ns += __shfl_down(ns, off);
        ds += __shfl_down(ds, off);
    }
    const int wid = threadIdx.x >> 6, lane = threadIdx.x & 63;
    if (lane == 0) { scratch[wid] = ns; scratch[4 + wid] = ds; }
    __syncthreads();
    if (threadIdx.x == 0) {
        double Nv = scratch[0] + scratch[1] + scratch[2] + scratch[3];
        double Dv = scratch[4] + scratch[5] + scratch[6] + scratch[7];
        out[b * 4 + s] = (float)(Nv / Dv);
    }
}

// ---------------- persistent cooperative kernel: whole pipeline, one launch ----------------
// Phases separated by grid.sync(); blocks grid-stride over tile units per phase.
// __syncthreads() at loop top guards shared-union reuse between units.
__global__ __launch_bounds__(256) void vif_persistent(
    const float* __restrict__ ref0, const float* __restrict__ dist0,
    float* __restrict__ ref1, float* __restrict__ dist1,
    float* __restrict__ ref2, float* __restrict__ dist2,
    float* __restrict__ ref3, float* __restrict__ dist3,
    double2* __restrict__ part, float* __restrict__ out) {
    __shared__ union SM {
        StatsSmem<17> s17; StatsSmem<9> s9; StatsSmem<5> s5; StatsSmem<3> s3;
        DownSmem<9> d9; DownSmem<5> d5; DownSmem<3> d3;
    } u;
    cg::grid_group grid = cg::this_grid();

    double2* p0 = part;
    double2* p1 = p0 + B_ * N0_;
    double2* p2 = p1 + B_ * N1_;
    double2* p3 = p2 + B_ * N2_;

    // Phase A: stats<17>(L0) + down<9>(L0->L1)
    for (int t = blockIdx.x; t < B_ * (N0_ + ND1_); t += gridDim.x) {
        __syncthreads();
        if (t < B_ * N0_)
            stats_body<17>(u.s17, ref0, dist0, H0_, W0_, 128.0f, p0, SY0, SX0, t % N0_, t / N0_);
        else {
            int r = t - B_ * N0_;
            down_body<9>(u.d9, ref0, dist0, ref1, dist1, H0_, W0_, H1_, W1_, 128.0f, DGX1,
                         r % ND1_, r / ND1_);
        }
    }
    grid.sync();

    // Phase B: stats<9>(L1) + down<5>(L1->L2)
    for (int t = blockIdx.x; t < B_ * (N1_ + ND2_); t += gridDim.x) {
        __syncthreads();
        if (t < B_ * N1_)
            stats_body<9>(u.s9, ref1, dist1, H1_, W1_, 0.0f, p1, SY1, SX1, t % N1_, t / N1_);
        else {
            int r = t - B_ * N1_;
            down_body<5>(u.d5, ref1, dist1, ref2, dist2, H1_, W1_, H2_, W2_, 0.0f, DGX2,
                         r % ND2_, r / ND2_);
        }
    }
    grid.sync();

    // Phase C: stats<5>(L2) + down<3>(L2->L3)
    for (int t = blockIdx.x; t < B_ * (N2_ + ND3_); t += gridDim.x) {
        __syncthreads();
        if (t < B_ * N2_)
            stats_body<5>(u.s5, ref2, dist2, H2_, W2_, 0.0f, p2, SY2, SX2, t % N2_, t / N2_);
        else {
            int r = t - B_ * N2_;
            down_body<3>(u.d3, ref2, dist2, ref3, dist3, H2_, W2_, H3_, W3_, 0.0f, DGX3,
                         r % ND3_, r / ND3_);
        }
    }
    grid.sync();

    // Phase D: stats<3>(L3)
    for (int t = blockIdx.x; t < B_ * N3_; t += gridDim.x) {
        __syncthreads();
        stats_body<3>(u.s3, ref3, dist3, H3_, W3_, 0.0f, p3, SY3, SX3, t % N3_, t / N3_);
    }
    grid.sync();

    // Phase E: reduce (16 blocks)
    if (blockIdx.x < 16) {
        __syncthreads();
        reduce_body(part, out, blockIdx.x & 3, blockIdx.x >> 2, (double*)&u);
    }
}

// ---------------- fallback kernels (R7 5-launch path) ----------------
template <int NS, int ND>
__global__ __launch_bounds__(256) void fused_kernel(
    const float* __restrict__ sref, const float* __restrict__ sdist,
    int sh, int sw, float sshift, double2* __restrict__ partial, int sy, int sx,
    float* __restrict__ drout, float* __restrict__ ddout,
    int dh2, int dw2, int dgx, int nStats) {
    __shared__ union {
        StatsSmem<NS> s;
        DownSmem<ND>  d;
    } u;
    const int bx = blockIdx.x;
    const int b  = blockIdx.z;
    if (bx < nStats)
        stats_body<NS>(u.s, sref, sdist, sh, sw, sshift, partial, sy, sx, bx, b);
    else
        down_body<ND>(u.d, sref, sdist, drout, ddout, sh, sw, dh2, dw2, sshift, dgx,
                      bx - nStats, b);
}

template <int N>
__global__ __launch_bounds__(256) void stats_only_kernel(
    const float* __restrict__ refp, const float* __restrict__ distp,
    int h, int w, float shift, double2* __restrict__ partial, int sy, int sx) {
    __shared__ StatsSmem<N> sm;
    stats_body<N>(sm, refp, distp, h, w, shift, partial, sy, sx, blockIdx.x, blockIdx.z);
}

__global__ __launch_bounds__(256) void reduce_kernel(
    const double2* __restrict__ part, float* __restrict__ out) {
    __shared__ double scratch[8];
    reduce_body(part, out, blockIdx.x & 3, blockIdx.x >> 2, scratch);
}

extern "C" void kernel_launch(void* const* d_in, const int* in_sizes, int n_in,
                              void* d_out, int out_size, void* d_ws, size_t ws_size,
                              hipStream_t stream) {
    const float* ref  = (const float*)d_in[0];
    const float* dist = (const float*)d_in[1];
    float* out = (float*)d_out;

    char*  ws  = (char*)d_ws;
    size_t off = 0;
    auto alloc = [&](size_t bytes) -> void* {
        void* p = ws + off;
        off += (bytes + 255) & ~(size_t)255;
        return p;
    };
    float* ref1  = (float*)alloc((size_t)B_ * H1_ * W1_ * 4);
    float* dist1 = (float*)alloc((size_t)B_ * H1_ * W1_ * 4);
    float* ref2  = (float*)alloc((size_t)B_ * H2_ * W2_ * 4);
    float* dist2 = (float*)alloc((size_t)B_ * H2_ * W2_ * 4);
    float* ref3  = (float*)alloc((size_t)B_ * H3_ * W3_ * 4);
    float* dist3 = (float*)alloc((size_t)B_ * H3_ * W3_ * 4);

    double2* part = (double2*)alloc((size_t)B_ * (N0_ + N1_ + N2_ + N3_) * sizeof(double2));

    // Cooperative persistent launch: grid sized to guaranteed co-residency.
    int occ = 0;
    hipError_t oe = hipOccupancyMaxActiveBlocksPerMultiprocessor(&occ, vif_persistent, 256, 0);
    int perCU = (oe == hipSuccess && occ >= 1) ? occ : 1;
    if (perCU > 6) perCU = 6;
    const int nblk = 256 * perCU;

    const float* a_ref = ref;  const float* a_dist = dist;
    void* kargs[] = {
        (void*)&a_ref, (void*)&a_dist,
        (void*)&ref1, (void*)&dist1, (void*)&ref2, (void*)&dist2,
        (void*)&ref3, (void*)&dist3, (void*)&part, (void*)&out
    };
    hipError_t err = hipLaunchCooperativeKernel(
        vif_persistent, dim3(nblk), dim3(256), kargs, 0, stream);

    if (err != hipSuccess) {
        // Fallback: proven R7 5-launch path.
        double2* p0 = part;
        double2* p1 = p0 + B_ * N0_;
        double2* p2 = p1 + B_ * N1_;
        double2* p3 = p2 + B_ * N2_;
        dim3 blk(256);

        fused_kernel<17, 9><<<dim3(N0_ + ND1_, 1, B_), blk, 0, stream>>>(
            ref, dist, H0_, W0_, 128.0f, p0, SY0, SX0,
            ref1, dist1, H1_, W1_, DGX1, N0_);
        fused_kernel<9, 5><<<dim3(N1_ + ND2_, 1, B_), blk, 0, stream>>>(
            ref1, dist1, H1_, W1_, 0.0f, p1, SY1, SX1,
            ref2, dist2, H2_, W2_, DGX2, N1_);
        fused_kernel<5, 3><<<dim3(N2_ + ND3_, 1, B_), blk, 0, stream>>>(
            ref2, dist2, H2_, W2_, 0.0f, p2, SY2, SX2,
            ref3, dist3, H3_, W3_, DGX3, N2_);
        stats_only_kernel<3><<<dim3(N3_, 1, B_), blk, 0, stream>>>(
            ref3, dist3, H3_, W3_, 0.0f, p3, SY3, SX3);
        reduce_kernel<<<16, 256, 0, stream>>>(part, out);
    }
}

// Round 9
// 260.863 us; speedup vs baseline: 1.8304x; 1.8304x over previous
//
#include <hip/hip_runtime.h>
#include <math.h>

#define VIF_EPS       1e-10f
#define SIGMA_NSQ     2.0f
#define SIGMA_MAX_INV (4.0f / (255.0f * 255.0f))
#define GAIN_LIMIT    100.0f

// jnp.pad mode='reflect' (no edge duplication). Overshoot < dim, single reflection suffices.
__device__ __forceinline__ int reflect_idx(int i, int n) {
    i = (i < 0) ? -i : i;
    i = (i >= n) ? (2 * n - 2 - i) : i;
    return i;
}

// Per-thread (all-lane, redundant) weight computation: parallel expf, no LDS,
// no barrier, no thread0-serial prologue. Division kept (not 1/s mul) for
// bit-match with the reference-matching earlier rounds.
template <int N>
__device__ __forceinline__ void weights_reg(float* wr) {
    const float sigma = (float)N / 5.0f;
    const float denom = 2.0f * sigma * sigma;
    float s = 0.0f;
#pragma unroll
    for (int i = 0; i < N; ++i) {
        float x = (float)i - (float)(N - 1) * 0.5f;
        wr[i] = expf(-(x * x) / denom);
        s += wr[i];
    }
#pragma unroll
    for (int i = 0; i < N; ++i) wr[i] = wr[i] / s;
}

constexpr int tile_w(int N) { return (128 - (N - 1)) & ~3; }  // 17->112, 9->120, 5/3->124
constexpr int cdiv(int a, int b) { return (a + b - 1) / b; }

// ---- pyramid constants ----
constexpr int B_ = 4;
constexpr int H0_ = 1080, W0_ = 1920;
constexpr int H1_ = 540,  W1_ = 960;
constexpr int H2_ = 270,  W2_ = 480;
constexpr int H3_ = 135,  W3_ = 240;

constexpr int SX0 = cdiv(W0_, tile_w(17)), SY0 = cdiv(H0_, 8);  // 18 x 135
constexpr int SX1 = cdiv(W1_, tile_w(9)),  SY1 = cdiv(H1_, 8);  // 8 x 68
constexpr int SX2 = cdiv(W2_, tile_w(5)),  SY2 = cdiv(H2_, 8);  // 4 x 34
constexpr int SX3 = cdiv(W3_, tile_w(3)),  SY3 = cdiv(H3_, 8);  // 2 x 17

constexpr int KY0 = 3, KY1 = 2, KY2 = 2, KY3 = 2;
constexpr int SYB0 = cdiv(SY0, KY0), NS0 = SX0 * SYB0;  // 18*45 = 810
constexpr int SYB1 = cdiv(SY1, KY1), NS1 = SX1 * SYB1;  // 8*34  = 272
constexpr int SYB2 = cdiv(SY2, KY2), NS2 = SX2 * SYB2;  // 4*17  = 68
constexpr int SYB3 = cdiv(SY3, KY3), NS3 = SX3 * SYB3;  // 2*9   = 18

constexpr int DGX1 = W1_ / 120, ND1_ = DGX1 * cdiv(H1_, 8);  // 544
constexpr int DGX2 = W2_ / 120, ND2_ = DGX2 * cdiv(H2_, 8);  // 136
constexpr int DGX3 = W3_ / 120, ND3_ = DGX3 * cdiv(H3_, 8);  // 34

// ---- static shared layouts ----
struct StatsSmemV {
    float v[5][8][132];   // row stride 528 B = 33*16 -> float4-clean
    float rsum[8];
};
struct DownSmemV {
    float vb[2][8][252];
};

// ---------------- stats body: KY y-tiles per block, atomic finish ----------------
// Y-MAJOR flatten for L2 reuse of vertical halos; KY consecutive y-tiles per block.
// VGPR discipline: NO min-waves launch bound (R3: 930 MB spill), 4-wide phase 2
// (R5: 8-wide -> VGPR 96 -> collapse), no cross-phase union kernels (R8: VGPR 128).
template <int N, int KY>
__device__ __forceinline__ void stats_body(
    StatsSmemV& sm, const float* __restrict__ refp, const float* __restrict__ distp,
    int h, int w, float shift, double* __restrict__ accND,
    int syb, int sy, int bx, int b) {
    constexpr int P   = (N - 1) / 2;
    constexpr int VC  = 128;
    constexpr int TW  = tile_w(N);
    constexpr int TH  = 8;
    constexpr int Q   = 4;
    constexpr int LR  = Q + 2 * P;
    constexpr int XG  = TW / 4;
    constexpr int F4  = (N + 6) / 4;

    const int tid = threadIdx.x;
    const int xtile  = bx / syb;
    const int ytile0 = (bx % syb) * KY;
    const int x0 = xtile * TW;

    float wr[N];
    weights_reg<N>(wr);

    float num_t = 0.f, den_t = 0.f;

#pragma unroll 1
    for (int k = 0; k < KY; ++k) {
        const int yt = ytile0 + k;
        if (yt >= sy) break;
        const int y0 = yt * TH;
        __syncthreads();  // guard sm.v reuse across tiles

        // ---- Phase 1: vertical conv from global ----
        {
            const int c = tid & (VC - 1);
            const int g = tid >> 7;
            const int gx = reflect_idx(x0 + c - P, w);
            const float* rb = refp  + (size_t)b * h * w + gx;
            const float* db = distp + (size_t)b * h * w + gx;

            float acc[5][Q];
#pragma unroll
            for (int ch = 0; ch < 5; ++ch)
#pragma unroll
                for (int q = 0; q < Q; ++q) acc[ch][q] = 0.f;

            auto acc_push = [&](int i, float r, float d) {
                float p2 = r * r, p3 = d * d, p4 = r * d;
#pragma unroll
                for (int q = 0; q < Q; ++q) {
                    int j = i - q;
                    if (j >= 0 && j < N) {
                        float wj = wr[j];
                        acc[0][q] += wj * r;
                        acc[1][q] += wj * d;
                        acc[2][q] += wj * p2;
                        acc[3][q] += wj * p3;
                        acc[4][q] += wj * p4;
                    }
                }
            };

            const int rowlo = y0 + g * Q - P;
            if (rowlo >= 0 && rowlo + LR <= h) {
                // Interior fast path (wave-uniform): pointer walk, no reflect per row.
                const float* pr = rb + (size_t)rowlo * w;
                const float* pd = db + (size_t)rowlo * w;
#pragma unroll
                for (int i = 0; i < LR; ++i) {
                    float r = pr[0] - shift;
                    float d = pd[0] - shift;
                    pr += w; pd += w;
                    acc_push(i, r, d);
                }
            } else {
#pragma unroll
                for (int i = 0; i < LR; ++i) {
                    int gy = reflect_idx(rowlo + i, h);
                    float r = rb[(size_t)gy * w] - shift;
                    float d = db[(size_t)gy * w] - shift;
                    acc_push(i, r, d);
                }
            }
#pragma unroll
            for (int ch = 0; ch < 5; ++ch)
#pragma unroll
                for (int q = 0; q < Q; ++q)
                    sm.v[ch][g * Q + q][c] = acc[ch][q];
        }
        __syncthreads();

        // ---- Phase 2: horizontal conv + VIF math (4 outputs/thread) ----
        {
            const int xg  = tid & 31;
            const int row = tid >> 5;
            if (xg < XG) {
                float mu[5][4];
#pragma unroll
                for (int ch = 0; ch < 5; ++ch) {
                    float win[F4 * 4];
                    const float4* s4 = (const float4*)&sm.v[ch][row][xg * 4];
#pragma unroll
                    for (int f = 0; f < F4; ++f) {
                        float4 t = s4[f];
                        win[4 * f + 0] = t.x; win[4 * f + 1] = t.y;
                        win[4 * f + 2] = t.z; win[4 * f + 3] = t.w;
                    }
#pragma unroll
                    for (int q = 0; q < 4; ++q) {
                        float a = 0.f;
#pragma unroll
                        for (int j = 0; j < N; ++j) a += wr[j] * win[q + j];
                        mu[ch][q] = a;
                    }
                }
                const int gy = y0 + row;
#pragma unroll
                for (int q = 0; q < 4; ++q) {
                    int gx = x0 + xg * 4 + q;
                    if (gx < w && gy < h) {
                        float mu1 = mu[0][q], mu2 = mu[1][q];
                        float s1  = fmaxf(0.f, mu[2][q] - mu1 * mu1);
                        float s2  = fmaxf(0.f, mu[3][q] - mu2 * mu2);
                        float s12 = mu[4][q] - mu1 * mu2;

                        float g  = s12 / (s1 + VIF_EPS);
                        float sv = s2 - g * s12;
                        if (s1 < VIF_EPS) { g = 0.f; sv = s2; s1 = 0.f; }
                        if (s2 < VIF_EPS) { g = 0.f; sv = 0.f; }
                        if (g  < 0.f)     { sv = s2; g = 0.f; }
                        if (sv <= VIF_EPS) sv = VIF_EPS;
                        g = fminf(g, GAIN_LIMIT);

                        float num_ar = __log2f(1.f + g * g * s1 / (sv + SIGMA_NSQ));
                        float den_ar = __log2f(1.f + s1 / SIGMA_NSQ);
                        if (s12 < 0.f) num_ar = 0.f;
                        if (s1 < SIGMA_NSQ) { num_ar = 1.f - s2 * SIGMA_MAX_INV; den_ar = 1.f; }
                        num_t += num_ar;
                        den_t += den_ar;
                    }
                }
            }
        }
    }

    // Single block reduction over all KY tiles, then one atomic pair.
#pragma unroll
    for (int off = 32; off > 0; off >>= 1) {
        num_t += __shfl_down(num_t, off);
        den_t += __shfl_down(den_t, off);
    }
    const int wid = tid >> 6, lane = tid & 63;
    if (lane == 0) { sm.rsum[wid] = num_t; sm.rsum[4 + wid] = den_t; }
    __syncthreads();
    if (tid == 0) {
        float ns = sm.rsum[0] + sm.rsum[1] + sm.rsum[2] + sm.rsum[3];
        float ds = sm.rsum[4] + sm.rsum[5] + sm.rsum[6] + sm.rsum[7];
        atomicAdd(&accND[0], (double)ns);
        atomicAdd(&accND[1], (double)ds);
    }
}

// ---------------- downsample body: vertical-first, 120x8 output tile (R7-proven) ----------------
template <int N>
__device__ __forceinline__ void down_body(
    DownSmemV& sm, const float* __restrict__ rin, const float* __restrict__ din,
    float* __restrict__ rout, float* __restrict__ dout,
    int h, int w, int h2, int w2, float shift, int dgx, int bx, int b) {
    constexpr int P   = (N - 1) / 2;
    constexpr int TOW = 120, TOH = 8;
    constexpr int IC  = 2 * (TOW - 1) + N;
    constexpr int NR  = 2 * (TOH - 1) + N;
    constexpr int XGn = TOW / 8;
    constexpr int WL  = 14 + N;
    constexpr int F4n = (WL + 3) / 4;

    float wr[N];
    weights_reg<N>(wr);

    const int tid = threadIdx.x;
    const int xt  = bx % dgx;
    const int yt  = bx / dgx;
    const int x0  = xt * TOW;
    const int y0  = yt * TOH;

    // ---- Vertical decimating pass ----
    if (tid < IC) {
        const int gx = reflect_idx(2 * x0 - P + tid, w);
        const int rowlo = 2 * y0 - P;
        const bool interior = (rowlo >= 0) && (rowlo + NR <= h);
#pragma unroll
        for (int img = 0; img < 2; ++img) {
            const float* src = (img ? din : rin) + (size_t)b * h * w + gx;
            float rows[NR];
            if (interior) {
                const float* p = src + (size_t)rowlo * w;
#pragma unroll
                for (int i = 0; i < NR; ++i) { rows[i] = p[0] - shift; p += w; }
            } else {
#pragma unroll
                for (int i = 0; i < NR; ++i)
                    rows[i] = src[(size_t)reflect_idx(rowlo + i, h) * w] - shift;
            }
#pragma unroll
            for (int t = 0; t < TOH; ++t) {
                float a = 0.f;
#pragma unroll
                for (int j = 0; j < N; ++j) a += wr[j] * rows[2 * t + j];
                sm.vb[img][t][tid] = a;
            }
        }
    }
    __syncthreads();

    // ---- Horizontal decimating pass ----
    if (tid < 2 * TOH * XGn) {
        const int img = tid / (TOH * XGn);
        const int rem = tid - img * (TOH * XGn);
        const int row = rem / XGn;
        const int xg  = rem - row * XGn;

        float win[F4n * 4];
        const float4* s4 = (const float4*)&sm.vb[img][row][16 * xg];
#pragma unroll
        for (int f = 0; f < F4n; ++f) {
            float4 t = s4[f];
            win[4 * f + 0] = t.x; win[4 * f + 1] = t.y;
            win[4 * f + 2] = t.z; win[4 * f + 3] = t.w;
        }
        float o[8];
#pragma unroll
        for (int q = 0; q < 8; ++q) {
            float a = 0.f;
#pragma unroll
            for (int j = 0; j < N; ++j) a += wr[j] * win[2 * q + j];
            o[q] = a;
        }
        const int gy = y0 + row;
        if (gy < h2) {
            float* outp = (img ? dout : rout) + (size_t)b * h2 * w2
                        + (size_t)gy * w2 + x0 + 8 * xg;
            *(float4*)outp       = make_float4(o[0], o[1], o[2], o[3]);
            *(float4*)(outp + 4) = make_float4(o[4], o[5], o[6], o[7]);
        }
    }
}

// ---------------- kernels ----------------
// acc layout: 16 x double2 {num, den} indexed by (b*4 + scale), then ticket u32.
template <int NS, int ND, int KY, int SCALE>
__global__ __launch_bounds__(256) void fused_kernel(
    const float* __restrict__ sref, const float* __restrict__ sdist,
    int sh, int sw, float sshift, double* __restrict__ acc, int syb, int sy,
    float* __restrict__ drout, float* __restrict__ ddout,
    int dh2, int dw2, int dgx, int nStats) {
    __shared__ union {
        StatsSmemV s;
        DownSmemV  d;
    } u;
    const int bx = blockIdx.x;
    const int b  = blockIdx.z;
    if (bx < nStats)
        stats_body<NS, KY>(u.s, sref, sdist, sh, sw, sshift,
                           acc + 2 * (b * 4 + SCALE), syb, sy, bx, b);
    else
        down_body<ND>(u.d, sref, sdist, drout, ddout, sh, sw, dh2, dw2, sshift, dgx,
                      bx - nStats, b);
}

// Final kernel: stats<3> + ticket; last block writes all 16 outputs.
template <int N, int KY>
__global__ __launch_bounds__(256) void final_kernel(
    const float* __restrict__ refp, const float* __restrict__ distp,
    int h, int w, double* __restrict__ acc, unsigned* __restrict__ ticket,
    int syb, int sy, int nTickets, float* __restrict__ out) {
    __shared__ StatsSmemV sm;
    const int b = blockIdx.z;
    stats_body<N, KY>(sm, refp, distp, h, w, 0.0f,
                      acc + 2 * (b * 4 + 3), syb, sy, blockIdx.x, b);
    if (threadIdx.x == 0) {
        __threadfence();
        unsigned old = atomicAdd(ticket, 1u);
        if (old == (unsigned)(nTickets - 1)) {
            // All stats<3> atomics done; earlier scales finalized at kernel boundaries.
            for (int i = 0; i < 16; ++i) {
                double nv = __hip_atomic_load(&acc[2 * i],     __ATOMIC_RELAXED,
                                              __HIP_MEMORY_SCOPE_AGENT);
                double dv = __hip_atomic_load(&acc[2 * i + 1], __ATOMIC_RELAXED,
                                              __HIP_MEMORY_SCOPE_AGENT);
                out[i] = (float)(nv / dv);
            }
        }
    }
}

extern "C" void kernel_launch(void* const* d_in, const int* in_sizes, int n_in,
                              void* d_out, int out_size, void* d_ws, size_t ws_size,
                              hipStream_t stream) {
    const float* ref  = (const float*)d_in[0];
    const float* dist = (const float*)d_in[1];
    float* out = (float*)d_out;

    char*  ws  = (char*)d_ws;
    size_t off = 0;
    auto alloc = [&](size_t bytes) -> void* {
        void* p = ws + off;
        off += (bytes + 255) & ~(size_t)255;
        return p;
    };
    float* ref1  = (float*)alloc((size_t)B_ * H1_ * W1_ * 4);
    float* dist1 = (float*)alloc((size_t)B_ * H1_ * W1_ * 4);
    float* ref2  = (float*)alloc((size_t)B_ * H2_ * W2_ * 4);
    float* dist2 = (float*)alloc((size_t)B_ * H2_ * W2_ * 4);
    float* ref3  = (float*)alloc((size_t)B_ * H3_ * W3_ * 4);
    float* dist3 = (float*)alloc((size_t)B_ * H3_ * W3_ * 4);

    double*   acc    = (double*)alloc(16 * sizeof(double2) + 64);
    unsigned* ticket = (unsigned*)((char*)acc + 16 * sizeof(double2));

    // Zero accumulators + ticket (ws is poisoned 0xAA before every timed call).
    hipMemsetAsync(acc, 0, 16 * sizeof(double2) + 64, stream);

    dim3 blk(256);

    // K1: stats<17>(L0, KY=3) + down<9>(L0 -> L1)
    fused_kernel<17, 9, KY0, 0><<<dim3(NS0 + ND1_, 1, B_), blk, 0, stream>>>(
        ref, dist, H0_, W0_, 128.0f, acc, SYB0, SY0,
        ref1, dist1, H1_, W1_, DGX1, NS0);

    // K2: stats<9>(L1, KY=2) + down<5>(L1 -> L2)
    fused_kernel<9, 5, KY1, 1><<<dim3(NS1 + ND2_, 1, B_), blk, 0, stream>>>(
        ref1, dist1, H1_, W1_, 0.0f, acc, SYB1, SY1,
        ref2, dist2, H2_, W2_, DGX2, NS1);

    // K3: stats<5>(L2, KY=2) + down<3>(L2 -> L3)
    fused_kernel<5, 3, KY2, 2><<<dim3(NS2 + ND3_, 1, B_), blk, 0, stream>>>(
        ref2, dist2, H2_, W2_, 0.0f, acc, SYB2, SY2,
        ref3, dist3, H3_, W3_, DGX3, NS2);

    // K4: stats<3>(L3, KY=2) + ticket finalize (writes all 16 outputs)
    final_kernel<3, KY3><<<dim3(NS3, 1, B_), blk, 0, stream>>>(
        ref3, dist3, H3_, W3_, acc, ticket, SYB3, SY3, NS3 * B_, out);
}